// Round 7
// baseline (185.462 us; speedup 1.0000x reference)
//
#include <hip/hip_runtime.h>
#include <stdint.h>

typedef unsigned short u16;
using f32x4 = __attribute__((ext_vector_type(4))) float;
using s16x8 = __attribute__((ext_vector_type(8))) short;

#define MFMA_BF16(a, b, c) __builtin_amdgcn_mfma_f32_16x16x32_bf16((a), (b), (c), 0, 0, 0)

#define GLOAD_LDS16(gptr, lptr)                                                               \
  __builtin_amdgcn_global_load_lds((const __attribute__((address_space(1))) uint32_t*)(gptr), \
                                   (__attribute__((address_space(3))) uint32_t*)(lptr), 16, 0, 0)

__device__ __forceinline__ u16 f2bf(float f) {
  union { float f; uint32_t u; } v; v.f = f;
  uint32_t r = v.u + 0x7fffu + ((v.u >> 16) & 1u);
  return (u16)(r >> 16);
}
__device__ __forceinline__ float bf2f(u16 h) {
  union { uint32_t u; float f; } v; v.u = ((uint32_t)h) << 16;
  return v.f;
}

// ---------------- K1: convert weights fp32 -> bf16 ----------------
__global__ void k_convert_w(const float* __restrict__ wq, const float* __restrict__ wo,
                            u16* __restrict__ wqb, u16* __restrict__ wob) {
  int i = blockIdx.x * 256 + threadIdx.x;
  const int nq = 1536 * 512 / 4;
  const int no = 512 * 512 / 4;
  if (i < nq) {
    float4 v = ((const float4*)wq)[i];
    u16* o = wqb + i * 4;
    o[0] = f2bf(v.x); o[1] = f2bf(v.y); o[2] = f2bf(v.z); o[3] = f2bf(v.w);
  } else if (i < nq + no) {
    int j = i - nq;
    float4 v = ((const float4*)wo)[j];
    u16* o = wob + j * 4;
    o[0] = f2bf(v.x); o[1] = f2bf(v.y); o[2] = f2bf(v.z); o[3] = f2bf(v.w);
  }
}

// ---------------- K2: x [b][c][t] f32 -> xT [b][t][c] bf16 ----------------
__global__ void k_transpose_x(const float* __restrict__ x, u16* __restrict__ xT) {
  __shared__ u16 tile[64][65];
  int b = blockIdx.z, c0 = blockIdx.y * 64, t0 = blockIdx.x * 64;
  const float* xp = x + ((size_t)b * 512 + c0) * 4096 + t0;
#pragma unroll
  for (int i = 0; i < 16; ++i) {
    int idx = threadIdx.x + i * 256;
    int r = idx >> 6, col = idx & 63;
    tile[r][col] = f2bf(xp[(size_t)r * 4096 + col]);
  }
  __syncthreads();
  u16* op = xT + ((size_t)b * 4096 + t0) * 512 + c0;
#pragma unroll
  for (int i = 0; i < 16; ++i) {
    int idx = threadIdx.x + i * 256;
    int r = idx >> 6, col = idx & 63;
    op[(size_t)r * 512 + col] = tile[col][r];
  }
}

// ---------------- K3: qkv GEMM (m97 structure) with fused epilogues ----------------
// A = w_qkv bf16 [1536][512]; BT = xT [b][4096][512]
// blockIdx.y 0..3 (q, 128 rows): softmax over d, *SCALE -> qT [bh][t][64]
// blockIdx.y 4..11 (kv, head h=y-4): A rows 0..63 = k-head rows, 64..127 = v-head rows.
//   Epilogue: ek=exp(k-acc) & v staged to LDS; ctx-MFMA 64x64 over n=128 ->
//   ctxp[bh][s][d][e] f32 partial + spart[bh][s][d] row-sums. k,v never hit HBM.
__launch_bounds__(256, 2)
__global__ void k_gemm_qkv(const u16* __restrict__ A, const u16* __restrict__ BT,
                           u16* __restrict__ qT, float* __restrict__ ctxp,
                           float* __restrict__ spart) {
  __shared__ __align__(16) char ldsbuf[35328];
  s16x8* As8 = (s16x8*)ldsbuf;             // [128 rows][8 chunks], chunk ^= (row&7)
  s16x8* Bs8 = (s16x8*)(ldsbuf + 16384);
  int b = blockIdx.z;
  int m0 = blockIdx.y * 128, n0 = blockIdx.x * 128;
  const u16 *Ab0, *Ab1;
  if (blockIdx.y < 4) {
    Ab0 = A + (size_t)m0 * 512;
    Ab1 = A + (size_t)(m0 + 64) * 512;
  } else {
    int h = (int)blockIdx.y - 4;
    Ab0 = A + (size_t)(512 + h * 64) * 512;   // k-head rows
    Ab1 = A + (size_t)(1024 + h * 64) * 512;  // v-head rows
  }
  const u16* Bb = BT + ((size_t)b * 4096 + n0) * 512;
  int tid = threadIdx.x, w = tid >> 6, lane = tid & 63;
  int hi = lane >> 4, lo = lane & 15;
  int wm = (w >> 1) * 64, wn = (w & 1) * 64;
  f32x4 acc[4][4] = {};
  for (int kt = 0; kt < 8; ++kt) {
    if (kt) __syncthreads();
#pragma unroll
    for (int it = 0; it < 4; ++it) {
      int L = (w * 4 + it) * 64 + lane;
      int r = L >> 3;
      int lc = (L & 7) ^ (r & 7);
      const u16* abase = ((w * 4 + it) < 8) ? Ab0 : Ab1;
      int rr = r & 63;
      GLOAD_LDS16(abase + (size_t)rr * 512 + kt * 64 + lc * 8, ((char*)As8) + (w * 4 + it) * 1024);
      GLOAD_LDS16(Bb + (size_t)r * 512 + kt * 64 + lc * 8, ((char*)Bs8) + (w * 4 + it) * 1024);
    }
    asm volatile("s_waitcnt vmcnt(0)");
    __syncthreads();
#pragma unroll
    for (int kk = 0; kk < 2; ++kk) {
      int cb = kk * 4 + hi;
      s16x8 af[4], bfr[4];
#pragma unroll
      for (int mi = 0; mi < 4; ++mi) {
        int r = wm + mi * 16 + lo;
        af[mi] = As8[r * 8 + (cb ^ (r & 7))];
      }
#pragma unroll
      for (int ni = 0; ni < 4; ++ni) {
        int r = wn + ni * 16 + lo;
        bfr[ni] = Bs8[r * 8 + (cb ^ (r & 7))];
      }
#pragma unroll
      for (int mi = 0; mi < 4; ++mi)
#pragma unroll
        for (int ni = 0; ni < 4; ++ni)
          acc[mi][ni] = MFMA_BF16(af[mi], bfr[ni], acc[mi][ni]);
    }
  }
  __syncthreads();  // LDS about to be reused by kv epilogue
  if (blockIdx.y < 4) {
    // ---- q softmax epilogue (proven) ----
    int head = (m0 >> 6) + (wm >> 6);
    int bh = b * 8 + head;
#pragma unroll
    for (int ni = 0; ni < 4; ++ni) {
      float mx = -1e30f;
#pragma unroll
      for (int mi = 0; mi < 4; ++mi)
#pragma unroll
        for (int j = 0; j < 4; ++j) mx = fmaxf(mx, acc[mi][ni][j]);
      mx = fmaxf(mx, __shfl_xor(mx, 16));
      mx = fmaxf(mx, __shfl_xor(mx, 32));
      float e[4][4];
      float s = 0.f;
#pragma unroll
      for (int mi = 0; mi < 4; ++mi)
#pragma unroll
        for (int j = 0; j < 4; ++j) { e[mi][j] = __expf(acc[mi][ni][j] - mx); s += e[mi][j]; }
      s += __shfl_xor(s, 16);
      s += __shfl_xor(s, 32);
      float sc = 0.125f / s;  // SCALE = 64^-0.5
      int t = n0 + wn + ni * 16 + lo;
      u16* op = qT + ((size_t)bh * 4096 + t) * 64 + hi * 4;
#pragma unroll
      for (int mi = 0; mi < 4; ++mi) {
        union { u16 u[4]; uint2 v; } pk;
#pragma unroll
        for (int j = 0; j < 4; ++j) pk.u[j] = f2bf(e[mi][j] * sc);
        *(uint2*)(op + mi * 16) = pk.v;
      }
    }
  } else {
    // ---- kv context epilogue ----
    int h = (int)blockIdx.y - 4;
    int bh = b * 8 + h;
    int s = blockIdx.x;                    // 32 slices of 128 t
    u16* ekl = (u16*)ldsbuf;               // [64][136] bf16 exp(k); stride 272B (2-way free)
    u16* vtl = (u16*)(ldsbuf + 17408);     // [64][136] bf16 v
    float* sums = (float*)(ldsbuf + 34816);  // [2][64] per-n-half row sums
    if (wm == 0) {
      // k-waves: exp + stage + row-sum
      float rsum[4][4];
#pragma unroll
      for (int mi = 0; mi < 4; ++mi)
#pragma unroll
        for (int j = 0; j < 4; ++j) {
          float t = 0.f;
#pragma unroll
          for (int ni = 0; ni < 4; ++ni) {
            float e = __expf(acc[mi][ni][j]);
            ekl[(mi * 16 + hi * 4 + j) * 136 + wn + ni * 16 + lo] = f2bf(e);
            t += e;
          }
          rsum[mi][j] = t;
        }
#pragma unroll
      for (int mi = 0; mi < 4; ++mi)
#pragma unroll
        for (int j = 0; j < 4; ++j) {
#pragma unroll
          for (int msk = 1; msk <= 8; msk <<= 1) rsum[mi][j] += __shfl_xor(rsum[mi][j], msk);
        }
      if (lo == 0) {
#pragma unroll
        for (int mi = 0; mi < 4; ++mi)
#pragma unroll
          for (int j = 0; j < 4; ++j) sums[(w & 1) * 64 + mi * 16 + hi * 4 + j] = rsum[mi][j];
      }
    } else {
      // v-waves: stage v
#pragma unroll
      for (int mi = 0; mi < 4; ++mi)
#pragma unroll
        for (int j = 0; j < 4; ++j)
#pragma unroll
          for (int ni = 0; ni < 4; ++ni)
            vtl[(mi * 16 + hi * 4 + j) * 136 + wn + ni * 16 + lo] = f2bf(acc[mi][ni][j]);
    }
    __syncthreads();
    // ctx-MFMA: wave w owns d-strip [w*16, w*16+16); K = n (128)
    int d0 = w * 16;
    f32x4 c2[4] = {};
#pragma unroll
    for (int kk = 0; kk < 4; ++kk) {
      s16x8 ae = *(const s16x8*)&ekl[(d0 + lo) * 136 + kk * 32 + hi * 8];
#pragma unroll
      for (int ni = 0; ni < 4; ++ni) {
        s16x8 bv = *(const s16x8*)&vtl[(ni * 16 + lo) * 136 + kk * 32 + hi * 8];
        c2[ni] = MFMA_BF16(ae, bv, c2[ni]);
      }
    }
    float* cp = ctxp + ((size_t)bh * 32 + s) * 4096;
#pragma unroll
    for (int ni = 0; ni < 4; ++ni)
#pragma unroll
      for (int j = 0; j < 4; ++j)
        cp[(size_t)(d0 + hi * 4 + j) * 64 + ni * 16 + lo] = c2[ni][j];
    if (w == 0) {
      // spart: sums were written pre-barrier
      spart[((size_t)bh * 32 + s) * 64 + lane] = sums[lane] + sums[64 + lane];
    }
  }
}

// ---------------- K4: reduce ctx partials + normalize + Wfused, all in one ----------------
// Bg[d][e] = (sum_s ctxp[bh][s][d][e]) / (sum_s spart[bh][s][d])   (staged in LDS)
// Wf[b][m][h*64+d] = sum_e wout[m][h*64+e] * Bg[d][e]
__global__ void k_ctx_wfused(const float* __restrict__ ctxp, const float* __restrict__ spart,
                             const u16* __restrict__ wout, u16* __restrict__ Wf) {
  __shared__ float sinv[64];
  __shared__ __align__(16) u16 Bgl[64 * 72];  // stride 144B -> 2-way free
  int bh = blockIdx.x;
  int b = bh >> 3, h = bh & 7;
  int tid = threadIdx.x;
  if (tid < 64) {
    float ssum = 0.f;
#pragma unroll 8
    for (int s = 0; s < 32; ++s) ssum += spart[((size_t)bh * 32 + s) * 64 + tid];
    sinv[tid] = 1.f / ssum;
  }
  __syncthreads();
  const float* cb = ctxp + (size_t)bh * 32 * 4096;
#pragma unroll
  for (int i = 0; i < 16; ++i) {
    int pos = i * 256 + tid;
    float v = 0.f;
#pragma unroll 8
    for (int s = 0; s < 32; ++s) v += cb[(size_t)s * 4096 + pos];
    int d = pos >> 6, e = pos & 63;
    Bgl[d * 72 + e] = f2bf(v * sinv[d]);
  }
  __syncthreads();
  int w = tid >> 6, lane = tid & 63, hi = lane >> 4, lo = lane & 15;
  const u16* Ab = wout + (size_t)h * 64;
  f32x4 acc[8][4] = {};
#pragma unroll
  for (int ks = 0; ks < 2; ++ks) {
    s16x8 bfr[4];
#pragma unroll
    for (int ni = 0; ni < 4; ++ni)
      bfr[ni] = *(const s16x8*)&Bgl[(ni * 16 + lo) * 72 + ks * 32 + hi * 8];
#pragma unroll
    for (int mi = 0; mi < 8; ++mi) {
      s16x8 a = *(const s16x8*)(Ab + (size_t)(w * 128 + mi * 16 + lo) * 512 + ks * 32 + hi * 8);
#pragma unroll
      for (int ni = 0; ni < 4; ++ni) acc[mi][ni] = MFMA_BF16(a, bfr[ni], acc[mi][ni]);
    }
  }
#pragma unroll
  for (int mi = 0; mi < 8; ++mi)
#pragma unroll
    for (int ni = 0; ni < 4; ++ni) {
      int m = w * 128 + mi * 16 + hi * 4;
      int d = ni * 16 + lo;
#pragma unroll
      for (int j = 0; j < 4; ++j)
        Wf[((size_t)b * 512 + m + j) * 512 + h * 64 + d] = f2bf(acc[mi][ni][j]);
    }
}

// ---------------- K5: final GEMM  y[b][m][t] = sum_hd Wf[b][m][hd]*qT[bh][t][d] + bias ------
__launch_bounds__(256, 2)
__global__ void k_gemm_final(const u16* __restrict__ Wf, const u16* __restrict__ qT,
                             u16* __restrict__ Ybf, const float* __restrict__ bias,
                             float2* __restrict__ part2) {
  __shared__ s16x8 As8[1024];
  __shared__ s16x8 Bs8[1024];
  int b = blockIdx.z;
  int m0 = blockIdx.y * 128, n0 = blockIdx.x * 128;
  const u16* Ab = Wf + ((size_t)b * 512 + m0) * 512;
  const u16* qTb = qT + (size_t)b * 8 * 4096 * 64;
  int tid = threadIdx.x, w = tid >> 6, lane = tid & 63;
  int wm = (w >> 1) * 64, wn = (w & 1) * 64;
  f32x4 acc[4][4] = {};
  for (int kt = 0; kt < 8; ++kt) {
    if (kt) __syncthreads();
#pragma unroll
    for (int it = 0; it < 4; ++it) {
      int L = (w * 4 + it) * 64 + lane;
      int r = L >> 3;
      int lc = (L & 7) ^ (r & 7);
      GLOAD_LDS16(Ab + (size_t)r * 512 + kt * 64 + lc * 8, ((char*)As8) + (w * 4 + it) * 1024);
      int G = kt * 8 + lc;  // global K-chunk: head = G>>3, d-chunk = G&7
      GLOAD_LDS16(qTb + ((size_t)(G >> 3) * 4096 + n0 + r) * 64 + (G & 7) * 8,
                  ((char*)Bs8) + (w * 4 + it) * 1024);
    }
    asm volatile("s_waitcnt vmcnt(0)");
    __syncthreads();
#pragma unroll
    for (int kk = 0; kk < 2; ++kk) {
      int cb = kk * 4 + (lane >> 4);
      s16x8 af[4], bfr[4];
#pragma unroll
      for (int mi = 0; mi < 4; ++mi) {
        int r = wm + mi * 16 + (lane & 15);
        af[mi] = As8[r * 8 + (cb ^ (r & 7))];
      }
#pragma unroll
      for (int ni = 0; ni < 4; ++ni) {
        int r = wn + ni * 16 + (lane & 15);
        bfr[ni] = Bs8[r * 8 + (cb ^ (r & 7))];
      }
#pragma unroll
      for (int mi = 0; mi < 4; ++mi)
#pragma unroll
        for (int ni = 0; ni < 4; ++ni)
          acc[mi][ni] = MFMA_BF16(af[mi], bfr[ni], acc[mi][ni]);
    }
  }
  u16* Yb = Ybf + ((size_t)b * 512 + m0) * 4096 + n0;
  float sm = 0.f, ssm = 0.f;
#pragma unroll
  for (int mi = 0; mi < 4; ++mi)
#pragma unroll
    for (int j = 0; j < 4; ++j) {
      int mm = wm + mi * 16 + (lane >> 4) * 4 + j;
      float bo = bias[m0 + mm];
#pragma unroll
      for (int ni = 0; ni < 4; ++ni) {
        int nn = wn + ni * 16 + (lane & 15);
        float vv = acc[mi][ni][j] + bo;
        sm += vv;
        ssm += vv * vv;
        Yb[(size_t)mm * 4096 + nn] = f2bf(vv);
      }
    }
#pragma unroll
  for (int off = 32; off; off >>= 1) { sm += __shfl_xor(sm, off); ssm += __shfl_xor(ssm, off); }
  __shared__ float sr[4], ssr[4];
  if (lane == 0) { sr[w] = sm; ssr[w] = ssm; }
  __syncthreads();
  if (tid == 0) {
    float2 o;
    o.x = sr[0] + sr[1] + sr[2] + sr[3];
    o.y = ssr[0] + ssr[1] + ssr[2] + ssr[3];
    part2[((size_t)b * 4 + blockIdx.y) * 32 + blockIdx.x] = o;
  }
}

// ---------------- K6: GroupNorm normalize  ybf bf16 -> d_out f32 ----------------
__global__ void k_gn_norm(const u16* __restrict__ ybf, float* __restrict__ y,
                          const float2* __restrict__ part2,
                          const float* __restrict__ gamma, const float* __restrict__ beta) {
  int b = blockIdx.y;
  float s = 0.f, ss = 0.f;
#pragma unroll 8
  for (int i = 0; i < 128; ++i) { float2 pp = part2[b * 128 + i]; s += pp.x; ss += pp.y; }
  const float N = 512.f * 4096.f;
  float mu = s / N;
  float var = ss / N - mu * mu;
  float rstd = rsqrtf(var + 1e-5f);
  size_t base = ((size_t)b << 21) + (size_t)blockIdx.x * 16384;
  const s16x8* ip = (const s16x8*)(ybf + base);
  float4* opf = (float4*)(y + base);
#pragma unroll
  for (int i = 0; i < 8; ++i) {
    int idx = threadIdx.x + i * 256;
    int loc = (int)(blockIdx.x * 16384) + idx * 8;
    int c = loc >> 12;
    float g = gamma[c] * rstd, bt = beta[c];
    s16x8 v = ip[idx];
    float4 o0, o1;
    o0.x = (bf2f((u16)v[0]) - mu) * g + bt;
    o0.y = (bf2f((u16)v[1]) - mu) * g + bt;
    o0.z = (bf2f((u16)v[2]) - mu) * g + bt;
    o0.w = (bf2f((u16)v[3]) - mu) * g + bt;
    o1.x = (bf2f((u16)v[4]) - mu) * g + bt;
    o1.y = (bf2f((u16)v[5]) - mu) * g + bt;
    o1.z = (bf2f((u16)v[6]) - mu) * g + bt;
    o1.w = (bf2f((u16)v[7]) - mu) * g + bt;
    opf[idx * 2] = o0;
    opf[idx * 2 + 1] = o1;
  }
}

extern "C" void kernel_launch(void* const* d_in, const int* in_sizes, int n_in,
                              void* d_out, int out_size, void* d_ws, size_t ws_size,
                              hipStream_t stream) {
  const float* x     = (const float*)d_in[0];
  // d_in[1] = mask: adds 1e-12 to fp32 logits -> numerically dead; ignored.
  const float* wqkv  = (const float*)d_in[2];
  const float* wout  = (const float*)d_in[3];
  const float* bout  = (const float*)d_in[4];
  const float* gamma = (const float*)d_in[5];
  const float* beta  = (const float*)d_in[6];
  float* y = (float*)d_out;

  char* ws = (char*)d_ws;
  u16*    ybf   = (u16*)ws;                   //  33,554,432 B [8][512][4096] bf16
  u16*    qT    = (u16*)(ws + 33554432);      //  33,554,432 B [64][4096][64] bf16
  float*  ctxp  = (float*)(ws + 67108864);    //  33,554,432 B [64][32][64d][64e] f32
  float*  spart = (float*)(ws + 100663296);   //     524,288 B [64][32][64] f32
  u16*    wqkvb = (u16*)(ws + 101187584);     //   1,572,864 B
  u16*    woutb = (u16*)(ws + 102760448);     //     524,288 B
  u16*    Wfused= (u16*)(ws + 103284736);     //   4,194,304 B [8][512][512] bf16
  float2* part2 = (float2*)(ws + 107479040);  //       8,192 B
  u16*    xT    = (u16*)(ws + 107487232);     //  33,554,432 B [8][4096][512] bf16

  k_convert_w<<<1024, 256, 0, stream>>>(wqkv, wout, wqkvb, woutb);
  {
    dim3 g(64, 8, 8);
    k_transpose_x<<<g, 256, 0, stream>>>(x, xT);
  }
  {
    dim3 g(32, 12, 8);
    k_gemm_qkv<<<g, 256, 0, stream>>>(wqkvb, xT, qT, ctxp, spart);
  }
  k_ctx_wfused<<<64, 256, 0, stream>>>(ctxp, spart, woutb, Wfused);
  {
    dim3 g(32, 4, 8);
    k_gemm_final<<<g, 256, 0, stream>>>(Wfused, qT, ybf, bout, part2);
  }
  {
    dim3 g(128, 8);
    k_gn_norm<<<g, 256, 0, stream>>>(ybf, y, part2, gamma, beta);
  }
}

// Round 8
// 174.810 us; speedup vs baseline: 1.0609x; 1.0609x over previous
//
#include <hip/hip_runtime.h>
#include <stdint.h>

typedef unsigned short u16;
using f32x4 = __attribute__((ext_vector_type(4))) float;
using s16x8 = __attribute__((ext_vector_type(8))) short;

#define MFMA_BF16(a, b, c) __builtin_amdgcn_mfma_f32_16x16x32_bf16((a), (b), (c), 0, 0, 0)

#define GLOAD_LDS16(gptr, lptr)                                                               \
  __builtin_amdgcn_global_load_lds((const __attribute__((address_space(1))) uint32_t*)(gptr), \
                                   (__attribute__((address_space(3))) uint32_t*)(lptr), 16, 0, 0)

__device__ __forceinline__ u16 f2bf(float f) {
  union { float f; uint32_t u; } v; v.f = f;
  uint32_t r = v.u + 0x7fffu + ((v.u >> 16) & 1u);
  return (u16)(r >> 16);
}
__device__ __forceinline__ float bf2f(u16 h) {
  union { uint32_t u; float f; } v; v.u = ((uint32_t)h) << 16;
  return v.f;
}

// ---------------- K1: x transpose (f32->bf16, [b][c][t]->[b][t][c]) + weight convert ------
// blockIdx.z < 8: transpose 64x64 tile (float4 reads, short8 writes).
// blockIdx.z == 8: convert w_qkv/w_out fp32->bf16 (512 blocks, 2 float4 chunks each).
__global__ void k_transpose_x(const float* __restrict__ x, u16* __restrict__ xT,
                              const float* __restrict__ wq, const float* __restrict__ wo,
                              u16* __restrict__ wqb, u16* __restrict__ wob) {
  if (blockIdx.z == 8) {
    const int nq = 1536 * 512 / 4;
    const int no = 512 * 512 / 4;
    int bid = blockIdx.y * 64 + blockIdx.x;  // 0..511
#pragma unroll
    for (int rep = 0; rep < 2; ++rep) {
      int i = bid * 256 + threadIdx.x + rep * 131072;
      if (i < nq) {
        float4 v = ((const float4*)wq)[i];
        u16* o = wqb + i * 4;
        o[0] = f2bf(v.x); o[1] = f2bf(v.y); o[2] = f2bf(v.z); o[3] = f2bf(v.w);
      } else if (i < nq + no) {
        int j = i - nq;
        float4 v = ((const float4*)wo)[j];
        u16* o = wob + j * 4;
        o[0] = f2bf(v.x); o[1] = f2bf(v.y); o[2] = f2bf(v.z); o[3] = f2bf(v.w);
      }
    }
    return;
  }
  __shared__ u16 tile[64][68];
  int b = blockIdx.z, c0 = blockIdx.y * 64, t0 = blockIdx.x * 64;
  const float* xp = x + ((size_t)b * 512 + c0) * 4096 + t0;
#pragma unroll
  for (int it = 0; it < 4; ++it) {
    int r = it * 16 + (threadIdx.x >> 4), c4 = (threadIdx.x & 15) * 4;
    float4 v = *(const float4*)(xp + (size_t)r * 4096 + c4);
    tile[r][c4 + 0] = f2bf(v.x);
    tile[r][c4 + 1] = f2bf(v.y);
    tile[r][c4 + 2] = f2bf(v.z);
    tile[r][c4 + 3] = f2bf(v.w);
  }
  __syncthreads();
  u16* op = xT + ((size_t)b * 4096 + t0) * 512 + c0;
#pragma unroll
  for (int it = 0; it < 2; ++it) {
    int tr = it * 32 + (threadIdx.x >> 3), cb = (threadIdx.x & 7) * 8;
    s16x8 o;
#pragma unroll
    for (int jj = 0; jj < 8; ++jj) o[jj] = tile[cb + jj][tr];
    *(s16x8*)(op + (size_t)tr * 512 + cb) = o;
  }
}

// ---------------- K2: qkv GEMM (m97 structure) with fused epilogues ----------------
// A = w_qkv bf16 [1536][512]; BT = xT [b][4096][512]
// y 0..3  (q): softmax over d, *SCALE -> qT [bh][t][64]
// y 4..7  (k): write exp(k) bf16 to qkv_b k-region + per-slice row-sums -> spart
// y 8..11 (v): write raw v to qkv_b v-region
__launch_bounds__(256, 2)
__global__ void k_gemm_qkv(const u16* __restrict__ A, const u16* __restrict__ BT,
                           u16* __restrict__ C, u16* __restrict__ qT,
                           float* __restrict__ spart) {
  __shared__ s16x8 As8[1024];  // [128 rows][8 chunks], physical chunk = logical ^ (row&7)
  __shared__ s16x8 Bs8[1024];
  __shared__ float ksums[4][64];
  int b = blockIdx.z;
  int m0 = blockIdx.y * 128, n0 = blockIdx.x * 128;
  const u16* Ab = A + (size_t)m0 * 512;
  const u16* Bb = BT + ((size_t)b * 4096 + n0) * 512;
  int tid = threadIdx.x, w = tid >> 6, lane = tid & 63;
  int wm = (w >> 1) * 64, wn = (w & 1) * 64;
  f32x4 acc[4][4] = {};
  for (int kt = 0; kt < 8; ++kt) {
    if (kt) __syncthreads();
#pragma unroll
    for (int it = 0; it < 4; ++it) {
      int L = (w * 4 + it) * 64 + lane;
      int r = L >> 3;
      int lc = (L & 7) ^ (r & 7);
      GLOAD_LDS16(Ab + (size_t)r * 512 + kt * 64 + lc * 8, ((char*)As8) + (w * 4 + it) * 1024);
      GLOAD_LDS16(Bb + (size_t)r * 512 + kt * 64 + lc * 8, ((char*)Bs8) + (w * 4 + it) * 1024);
    }
    asm volatile("s_waitcnt vmcnt(0)");
    __syncthreads();
#pragma unroll
    for (int kk = 0; kk < 2; ++kk) {
      int cb = kk * 4 + (lane >> 4);
      s16x8 af[4], bfr[4];
#pragma unroll
      for (int mi = 0; mi < 4; ++mi) {
        int r = wm + mi * 16 + (lane & 15);
        af[mi] = As8[r * 8 + (cb ^ (r & 7))];
      }
#pragma unroll
      for (int ni = 0; ni < 4; ++ni) {
        int r = wn + ni * 16 + (lane & 15);
        bfr[ni] = Bs8[r * 8 + (cb ^ (r & 7))];
      }
#pragma unroll
      for (int mi = 0; mi < 4; ++mi)
#pragma unroll
        for (int ni = 0; ni < 4; ++ni)
          acc[mi][ni] = MFMA_BF16(af[mi], bfr[ni], acc[mi][ni]);
    }
  }
  if (blockIdx.y < 4) {
    // ---- q softmax epilogue ----
    int head = (m0 >> 6) + (wm >> 6);
    int bh = b * 8 + head;
#pragma unroll
    for (int ni = 0; ni < 4; ++ni) {
      float mx = -1e30f;
#pragma unroll
      for (int mi = 0; mi < 4; ++mi)
#pragma unroll
        for (int j = 0; j < 4; ++j) mx = fmaxf(mx, acc[mi][ni][j]);
      mx = fmaxf(mx, __shfl_xor(mx, 16));
      mx = fmaxf(mx, __shfl_xor(mx, 32));
      float e[4][4];
      float s = 0.f;
#pragma unroll
      for (int mi = 0; mi < 4; ++mi)
#pragma unroll
        for (int j = 0; j < 4; ++j) { e[mi][j] = __expf(acc[mi][ni][j] - mx); s += e[mi][j]; }
      s += __shfl_xor(s, 16);
      s += __shfl_xor(s, 32);
      float sc = 0.125f / s;  // SCALE = 64^-0.5
      int t = n0 + wn + ni * 16 + (lane & 15);
      u16* op = qT + ((size_t)bh * 4096 + t) * 64 + (lane >> 4) * 4;
#pragma unroll
      for (int mi = 0; mi < 4; ++mi) {
        union { u16 u[4]; uint2 v; } pk;
#pragma unroll
        for (int j = 0; j < 4; ++j) pk.u[j] = f2bf(e[mi][j] * sc);
        *(uint2*)(op + mi * 16) = pk.v;
      }
    }
  } else if (blockIdx.y < 8) {
    // ---- k epilogue: exp(k) + row-sums (no max: |k|<~6, exp safe in fp32) ----
    u16* Cb = C + ((size_t)b * 1536 + m0) * 4096 + n0;
#pragma unroll
    for (int mi = 0; mi < 4; ++mi)
#pragma unroll
      for (int j = 0; j < 4; ++j) {
        int mm = wm + mi * 16 + (lane >> 4) * 4 + j;
        float t = 0.f;
#pragma unroll
        for (int ni = 0; ni < 4; ++ni) {
          int nn = wn + ni * 16 + (lane & 15);
          float e = __expf(acc[mi][ni][j]);
          t += e;
          Cb[(size_t)mm * 4096 + nn] = f2bf(e);
        }
        t += __shfl_xor(t, 1);
        t += __shfl_xor(t, 2);
        t += __shfl_xor(t, 4);
        t += __shfl_xor(t, 8);
        if ((lane & 15) == 0) ksums[w][mi * 16 + (lane >> 4) * 4 + j] = t;
      }
    __syncthreads();
    if (tid < 128) {
      int hr = tid >> 6, r = tid & 63;
      float v = ksums[hr * 2][r] + ksums[hr * 2 + 1][r];
      // spart[b][hd][32 n-slices]; hd = (m0-512) + hr*64 + r
      spart[((size_t)b * 512 + (m0 - 512) + hr * 64 + r) * 32 + blockIdx.x] = v;
    }
  } else {
    // ---- v raw write ----
    u16* Cb = C + ((size_t)b * 1536 + m0) * 4096 + n0;
#pragma unroll
    for (int mi = 0; mi < 4; ++mi)
#pragma unroll
      for (int ni = 0; ni < 4; ++ni)
#pragma unroll
        for (int j = 0; j < 4; ++j) {
          int mm = wm + mi * 16 + (lane >> 4) * 4 + j;
          int nn = wn + ni * 16 + (lane & 15);
          Cb[(size_t)mm * 4096 + nn] = f2bf(acc[mi][ni][j]);
        }
  }
}

// ---------------- K3: context partials (pure stream+MFMA; exp(k) precomputed) ------------
// ctxp[bh][s][d][e] = sum_{n in slice s} ek[d][n] * v[e][n]   (f32, unnormalized)
__global__ void k_context_part(const u16* __restrict__ qkv, float* __restrict__ ctxp) {
  int s = blockIdx.x, bh = blockIdx.y;  // 16 slices x 64 bh
  int b = bh >> 3, h = bh & 7;
  int w = threadIdx.x >> 6, lane = threadIdx.x & 63;
  int hi = lane >> 4, lo = lane & 15;
  const u16* vb = qkv + ((size_t)b * 1536 + 1024 + h * 64) * 4096 + s * 256;
  const u16* kb = qkv + ((size_t)b * 1536 + 512 + h * 64) * 4096 + s * 256;  // holds exp(k)
  int d = w * 16 + lo;
  f32x4 acc[4] = {};
#pragma unroll
  for (int st = 0; st < 8; ++st) {
    int nn = st * 32 + hi * 8;
    s16x8 bexp = *(const s16x8*)(kb + (size_t)d * 4096 + nn);
#pragma unroll
    for (int ei = 0; ei < 4; ++ei) {
      s16x8 a = *(const s16x8*)(vb + (size_t)(ei * 16 + lo) * 4096 + nn);
      acc[ei] = MFMA_BF16(a, bexp, acc[ei]);
    }
  }
  // C frag: row (A-dim e) = ei*16 + hi*4 + j ; col (B-dim d) = w*16 + lo
  float* cp = ctxp + ((size_t)bh * 16 + s) * 4096;
#pragma unroll
  for (int ei = 0; ei < 4; ++ei) {
    float4 o;
    o.x = acc[ei][0]; o.y = acc[ei][1]; o.z = acc[ei][2]; o.w = acc[ei][3];
    *(float4*)&cp[(size_t)d * 64 + ei * 16 + hi * 4] = o;
  }
}

// ---------------- K4: reduce ctx partials + normalize -> Bg [bh][d][e] bf16 ----------------
__global__ void k_ctx_reduce(const float* __restrict__ ctxp, const float* __restrict__ spart,
                             u16* __restrict__ Bg) {
  int q = blockIdx.x, bh = blockIdx.y;  // q: 16 chunks of 256 positions (4 d-rows)
  int b = bh >> 3, h = bh & 7;
  __shared__ float sinv[4];
  int tid = threadIdx.x;
  if (tid < 4) {
    int hd = h * 64 + q * 4 + tid;
    const float* sp = spart + ((size_t)b * 512 + hd) * 32;
    float s = 0.f;
#pragma unroll
    for (int xx = 0; xx < 32; ++xx) s += sp[xx];
    sinv[tid] = 1.f / s;
  }
  __syncthreads();
  int pos = q * 256 + tid;
  float v = 0.f;
#pragma unroll
  for (int si = 0; si < 16; ++si) v += ctxp[((size_t)bh * 16 + si) * 4096 + pos];
  Bg[(size_t)bh * 4096 + pos] = f2bf(v * sinv[(pos >> 6) & 3]);
}

// ---------------- K5: Wfused[b][m][h*64+d] = sum_e wout[m][h*64+e] * Bg[bh][d][e] ----------
__global__ void k_wfused(const u16* __restrict__ wout, const u16* __restrict__ Bg,
                         u16* __restrict__ Wf) {
  int bh = blockIdx.x;
  int b = bh >> 3, h = bh & 7;
  int w = threadIdx.x >> 6, lane = threadIdx.x & 63;
  int hi = lane >> 4, lo = lane & 15;
  const u16* Bb = Bg + (size_t)bh * 4096;
  const u16* Ab = wout + (size_t)h * 64;
  f32x4 acc[8][4] = {};
#pragma unroll
  for (int ks = 0; ks < 2; ++ks) {
    s16x8 bfr[4];
#pragma unroll
    for (int ni = 0; ni < 4; ++ni)
      bfr[ni] = *(const s16x8*)(Bb + (size_t)(ni * 16 + lo) * 64 + ks * 32 + hi * 8);
#pragma unroll
    for (int mi = 0; mi < 8; ++mi) {
      s16x8 a = *(const s16x8*)(Ab + (size_t)(w * 128 + mi * 16 + lo) * 512 + ks * 32 + hi * 8);
#pragma unroll
      for (int ni = 0; ni < 4; ++ni) acc[mi][ni] = MFMA_BF16(a, bfr[ni], acc[mi][ni]);
    }
  }
#pragma unroll
  for (int mi = 0; mi < 8; ++mi)
#pragma unroll
    for (int ni = 0; ni < 4; ++ni) {
      int m = w * 128 + mi * 16 + hi * 4;
      int d = ni * 16 + lo;
#pragma unroll
      for (int j = 0; j < 4; ++j)
        Wf[((size_t)b * 512 + m + j) * 512 + h * 64 + d] = f2bf(acc[mi][ni][j]);
    }
}

// ---------------- K6: final GEMM  y[b][m][t] = sum_hd Wf[b][m][hd]*qT[bh][t][d] + bias ------
__launch_bounds__(256, 2)
__global__ void k_gemm_final(const u16* __restrict__ Wf, const u16* __restrict__ qT,
                             u16* __restrict__ Ybf, const float* __restrict__ bias,
                             float2* __restrict__ part2) {
  __shared__ s16x8 As8[1024];
  __shared__ s16x8 Bs8[1024];
  int b = blockIdx.z;
  int m0 = blockIdx.y * 128, n0 = blockIdx.x * 128;
  const u16* Ab = Wf + ((size_t)b * 512 + m0) * 512;
  const u16* qTb = qT + (size_t)b * 8 * 4096 * 64;
  int tid = threadIdx.x, w = tid >> 6, lane = tid & 63;
  int wm = (w >> 1) * 64, wn = (w & 1) * 64;
  f32x4 acc[4][4] = {};
  for (int kt = 0; kt < 8; ++kt) {
    if (kt) __syncthreads();
#pragma unroll
    for (int it = 0; it < 4; ++it) {
      int L = (w * 4 + it) * 64 + lane;
      int r = L >> 3;
      int lc = (L & 7) ^ (r & 7);
      GLOAD_LDS16(Ab + (size_t)r * 512 + kt * 64 + lc * 8, ((char*)As8) + (w * 4 + it) * 1024);
      int G = kt * 8 + lc;  // global K-chunk: head = G>>3, d-chunk = G&7
      GLOAD_LDS16(qTb + ((size_t)(G >> 3) * 4096 + n0 + r) * 64 + (G & 7) * 8,
                  ((char*)Bs8) + (w * 4 + it) * 1024);
    }
    asm volatile("s_waitcnt vmcnt(0)");
    __syncthreads();
#pragma unroll
    for (int kk = 0; kk < 2; ++kk) {
      int cb = kk * 4 + (lane >> 4);
      s16x8 af[4], bfr[4];
#pragma unroll
      for (int mi = 0; mi < 4; ++mi) {
        int r = wm + mi * 16 + (lane & 15);
        af[mi] = As8[r * 8 + (cb ^ (r & 7))];
      }
#pragma unroll
      for (int ni = 0; ni < 4; ++ni) {
        int r = wn + ni * 16 + (lane & 15);
        bfr[ni] = Bs8[r * 8 + (cb ^ (r & 7))];
      }
#pragma unroll
      for (int mi = 0; mi < 4; ++mi)
#pragma unroll
        for (int ni = 0; ni < 4; ++ni)
          acc[mi][ni] = MFMA_BF16(af[mi], bfr[ni], acc[mi][ni]);
    }
  }
  u16* Yb = Ybf + ((size_t)b * 512 + m0) * 4096 + n0;
  float sm = 0.f, ssm = 0.f;
#pragma unroll
  for (int mi = 0; mi < 4; ++mi)
#pragma unroll
    for (int j = 0; j < 4; ++j) {
      int mm = wm + mi * 16 + (lane >> 4) * 4 + j;
      float bo = bias[m0 + mm];
#pragma unroll
      for (int ni = 0; ni < 4; ++ni) {
        int nn = wn + ni * 16 + (lane & 15);
        float vv = acc[mi][ni][j] + bo;
        sm += vv;
        ssm += vv * vv;
        Yb[(size_t)mm * 4096 + nn] = f2bf(vv);
      }
    }
#pragma unroll
  for (int off = 32; off; off >>= 1) { sm += __shfl_xor(sm, off); ssm += __shfl_xor(ssm, off); }
  __shared__ float sr[4], ssr[4];
  if (lane == 0) { sr[w] = sm; ssr[w] = ssm; }
  __syncthreads();
  if (tid == 0) {
    float2 o;
    o.x = sr[0] + sr[1] + sr[2] + sr[3];
    o.y = ssr[0] + ssr[1] + ssr[2] + ssr[3];
    part2[((size_t)b * 4 + blockIdx.y) * 32 + blockIdx.x] = o;
  }
}

// ---------------- K7: GroupNorm normalize  ybf bf16 -> d_out f32 ----------------
__global__ void k_gn_norm(const u16* __restrict__ ybf, float* __restrict__ y,
                          const float2* __restrict__ part2,
                          const float* __restrict__ gamma, const float* __restrict__ beta) {
  int b = blockIdx.y;
  float s = 0.f, ss = 0.f;
#pragma unroll 8
  for (int i = 0; i < 128; ++i) { float2 pp = part2[b * 128 + i]; s += pp.x; ss += pp.y; }
  const float N = 512.f * 4096.f;
  float mu = s / N;
  float var = ss / N - mu * mu;
  float rstd = rsqrtf(var + 1e-5f);
  size_t base = ((size_t)b << 21) + (size_t)blockIdx.x * 16384;
  const s16x8* ip = (const s16x8*)(ybf + base);
  float4* opf = (float4*)(y + base);
#pragma unroll
  for (int i = 0; i < 8; ++i) {
    int idx = threadIdx.x + i * 256;
    int loc = (int)(blockIdx.x * 16384) + idx * 8;
    int c = loc >> 12;
    float g = gamma[c] * rstd, bt = beta[c];
    s16x8 v = ip[idx];
    float4 o0, o1;
    o0.x = (bf2f((u16)v[0]) - mu) * g + bt;
    o0.y = (bf2f((u16)v[1]) - mu) * g + bt;
    o0.z = (bf2f((u16)v[2]) - mu) * g + bt;
    o0.w = (bf2f((u16)v[3]) - mu) * g + bt;
    o1.x = (bf2f((u16)v[4]) - mu) * g + bt;
    o1.y = (bf2f((u16)v[5]) - mu) * g + bt;
    o1.z = (bf2f((u16)v[6]) - mu) * g + bt;
    o1.w = (bf2f((u16)v[7]) - mu) * g + bt;
    opf[idx * 2] = o0;
    opf[idx * 2 + 1] = o1;
  }
}

extern "C" void kernel_launch(void* const* d_in, const int* in_sizes, int n_in,
                              void* d_out, int out_size, void* d_ws, size_t ws_size,
                              hipStream_t stream) {
  const float* x     = (const float*)d_in[0];
  // d_in[1] = mask: adds 1e-12 to fp32 logits -> numerically dead; ignored.
  const float* wqkv  = (const float*)d_in[2];
  const float* wout  = (const float*)d_in[3];
  const float* bout  = (const float*)d_in[4];
  const float* gamma = (const float*)d_in[5];
  const float* beta  = (const float*)d_in[6];
  float* y = (float*)d_out;

  char* ws = (char*)d_ws;
  u16*    qkv_b = (u16*)ws;                   // 100,663,296 B [8][1536][4096] bf16 (exp(k), v)
  u16*    ybf   = (u16*)ws;                   //  overlay: 33,554,432 B [8][512][4096] bf16
  u16*    xT    = (u16*)(ws + 100663296);     //  33,554,432 B [8][4096][512] bf16 (dead after K2)
  float*  ctxp  = (float*)(ws + 100663296);   //  overlay: 16,777,216 B [64][16][64d][64e] f32
  u16*    Bg    = (u16*)(ws + 117702656);     //     524,288 B [64][4096] bf16
  u16*    qT    = (u16*)(ws + 134217728);     //  33,554,432 B [64][4096][64] bf16
  u16*    wqkvb = (u16*)(ws + 167772160);     //   1,572,864 B
  u16*    woutb = (u16*)(ws + 169345024);     //     524,288 B
  u16*    Wfused= (u16*)(ws + 169869312);     //   4,194,304 B [8][512][512] bf16
  float2* part2 = (float2*)(ws + 174063616);  //       8,192 B
  float*  spart = (float*)(ws + 174071808);   //     524,288 B [8][512][32] f32 (outside xT!)

  {
    dim3 g(64, 8, 9);  // z<8: transpose; z==8: weight convert
    k_transpose_x<<<g, 256, 0, stream>>>(x, xT, wqkv, wout, wqkvb, woutb);
  }
  {
    dim3 g(32, 12, 8);
    k_gemm_qkv<<<g, 256, 0, stream>>>(wqkvb, xT, qkv_b, qT, spart);
  }
  {
    dim3 g(16, 64);
    k_context_part<<<g, 256, 0, stream>>>(qkv_b, ctxp);
  }
  {
    dim3 g(16, 64);
    k_ctx_reduce<<<g, 256, 0, stream>>>(ctxp, spart, Bg);
  }
  k_wfused<<<64, 256, 0, stream>>>(woutb, Bg, Wfused);
  {
    dim3 g(32, 4, 8);
    k_gemm_final<<<g, 256, 0, stream>>>(Wfused, qT, ybf, bout, part2);
  }
  {
    dim3 g(128, 8);
    k_gn_norm<<<g, 256, 0, stream>>>(ybf, y, part2, gamma, beta);
  }
}